// Round 3
// baseline (352.204 us; speedup 1.0000x reference)
//
#include <hip/hip_runtime.h>

typedef unsigned short u16;
typedef unsigned int   u32;

typedef short s16x8 __attribute__((ext_vector_type(8)));
typedef float f32x4 __attribute__((ext_vector_type(4)));

static __device__ __forceinline__ u16 f2bf(float f) {
  u32 u = __float_as_uint(f);
  u = (u + 0x7fffu + ((u >> 16) & 1u)) >> 16;
  return (u16)u;
}
static __device__ __forceinline__ float bf2f(u16 h) {
  return __uint_as_float(((u32)h) << 16);
}
static __device__ __forceinline__ f32x4 mfma16(s16x8 a, s16x8 b, f32x4 c) {
  return __builtin_amdgcn_mfma_f32_16x16x32_bf16(a, b, c, 0, 0, 0);
}
static __device__ __forceinline__ void gload16(const u16* g, u16* l) {
  __builtin_amdgcn_global_load_lds(
      (const __attribute__((address_space(1))) void*)g,
      (__attribute__((address_space(3))) void*)l, 16, 0, 0);
}

// ---------------- flat f32 -> bf16 convert, 8 elems/thread ----------------
__global__ __launch_bounds__(256) void cvt_k(const float* __restrict__ in,
                                             u16* __restrict__ out, int n8) {
  int i = blockIdx.x * 256 + threadIdx.x;
  if (i >= n8) return;
  const float4* p = reinterpret_cast<const float4*>(in);
  float4 a = p[2 * i], b = p[2 * i + 1];
  union { u16 u[8]; uint4 v; } r;
  r.u[0] = f2bf(a.x); r.u[1] = f2bf(a.y); r.u[2] = f2bf(a.z); r.u[3] = f2bf(a.w);
  r.u[4] = f2bf(b.x); r.u[5] = f2bf(b.y); r.u[6] = f2bf(b.z); r.u[7] = f2bf(b.w);
  reinterpret_cast<uint4*>(out)[i] = r.v;
}

// ------------- transpose+convert: in [R,C] f32 -> out [C,R] bf16, batched -------------
__global__ void tcvt_k(const float* __restrict__ in, u16* __restrict__ out,
                       int R, int C, long long ibs, long long obs) {
  __shared__ float t[32][33];
  const float* ip = in + (size_t)blockIdx.z * ibs;
  u16* op = out + (size_t)blockIdx.z * obs;
  int r0 = blockIdx.y * 32, c0 = blockIdx.x * 32;
  int x = threadIdx.x, y = threadIdx.y;
  for (int i = y; i < 32; i += 8) t[i][x] = ip[(size_t)(r0 + i) * C + c0 + x];
  __syncthreads();
  for (int i = y; i < 32; i += 8) op[(size_t)(c0 + i) * R + r0 + x] = f2bf(t[x][i]);
}

// ------------- row softmax with mask, in-place f32 -> bf16 (row-local) -------------
__global__ __launch_bounds__(256) void softmax_k(const float* __restrict__ S,
                                                 const int* __restrict__ mask,
                                                 u16* __restrict__ P, float scale) {
  __shared__ float redm[4], reds[4];
  const int row = blockIdx.x;
  const int bb = row >> 11;
  const int tid = threadIdx.x;
  const float* s = S + (size_t)row * 2048;
  const int* mk = mask + (size_t)bb * 2048;
  float4 a = reinterpret_cast<const float4*>(s)[2 * tid];
  float4 c = reinterpret_cast<const float4*>(s)[2 * tid + 1];
  int4 ma = reinterpret_cast<const int4*>(mk)[2 * tid];
  int4 mc = reinterpret_cast<const int4*>(mk)[2 * tid + 1];
  float v[8];
  v[0] = ma.x ? a.x * scale : -1e30f;
  v[1] = ma.y ? a.y * scale : -1e30f;
  v[2] = ma.z ? a.z * scale : -1e30f;
  v[3] = ma.w ? a.w * scale : -1e30f;
  v[4] = mc.x ? c.x * scale : -1e30f;
  v[5] = mc.y ? c.y * scale : -1e30f;
  v[6] = mc.z ? c.z * scale : -1e30f;
  v[7] = mc.w ? c.w * scale : -1e30f;
  float mx = v[0];
  #pragma unroll
  for (int i = 1; i < 8; ++i) mx = fmaxf(mx, v[i]);
  for (int off = 32; off; off >>= 1) mx = fmaxf(mx, __shfl_xor(mx, off));
  if ((tid & 63) == 0) redm[tid >> 6] = mx;
  __syncthreads();
  mx = fmaxf(fmaxf(redm[0], redm[1]), fmaxf(redm[2], redm[3]));
  float sum = 0.f;
  #pragma unroll
  for (int i = 0; i < 8; ++i) { v[i] = __expf(v[i] - mx); sum += v[i]; }
  for (int off = 32; off; off >>= 1) sum += __shfl_xor(sum, off);
  if ((tid & 63) == 0) reds[tid >> 6] = sum;
  __syncthreads();
  sum = reds[0] + reds[1] + reds[2] + reds[3];
  float inv = 1.0f / sum;
  union { u16 u[8]; uint4 q; } r;
  #pragma unroll
  for (int i = 0; i < 8; ++i) r.u[i] = f2bf(v[i] * inv);
  reinterpret_cast<uint4*>(P + (size_t)row * 4096)[tid] = r.q;
}

// ======== 256x256-tile, 8-wave, double-buffered-prefetch bf16 GEMM ========
// A:[M,K] (lda), Bt:[N,K] (ldb), both bf16 row-major. K-split A/A2 on Ksplit,
// M-split Bt/Bt2 on Msp rows. EPI 0: relu->bf16 Cb | 1: f32 Cf | 3: gate.
template <int EPI>
__global__ __launch_bounds__(512, 2) void gemm256_k(
    const u16* __restrict__ A, const u16* __restrict__ A2,
    const u16* __restrict__ Bt, const u16* __restrict__ Bt2,
    float* __restrict__ Cf, u16* __restrict__ Cb,
    const float* __restrict__ R0, const u16* __restrict__ R1,
    int M, int N, int K, int lda, int ldb, int Ksplit, int Msp,
    long long A_bs, long long B_bs, long long C_bs) {
  __shared__ u16 As[2][256 * 64];
  __shared__ u16 Bs[2][256 * 64];
  const int tid = threadIdx.x;
  const int wave = tid >> 6, lane = tid & 63;
  const size_t Aoff = (size_t)blockIdx.z * A_bs;
  const size_t Boff = (size_t)blockIdx.z * B_bs;
  const size_t Coff = (size_t)blockIdx.z * C_bs;
  const int m0 = blockIdx.y * 256, n0 = blockIdx.x * 256;
  const int wr = wave >> 2, wc = wave & 3;      // 2 x 4 waves, each owns 128x64
  const int l15 = lane & 15, l4 = lane >> 4;
  const int srow = lane >> 3;                   // 0..7
  const int scol = (lane & 7) * 8;              // u16 col offset
  const u16* Bbase = ((m0 < Msp) ? Bt : Bt2) + Boff;

  f32x4 acc[8][4];
  #pragma unroll
  for (int i = 0; i < 8; ++i)
    #pragma unroll
    for (int j = 0; j < 4; ++j) acc[i][j] = (f32x4){0.f, 0.f, 0.f, 0.f};

  const int nt = K / 64;
  auto stage = [&](int buf, int k0) {
    const u16* Abase; int kloc;
    if (k0 < Ksplit) { Abase = A + Aoff;  kloc = k0; }
    else             { Abase = A2 + Aoff; kloc = k0 - Ksplit; }
    #pragma unroll
    for (int c = 0; c < 4; ++c) {
      int chunk = wave * 4 + c;                 // 0..31, 1KB each
      int row = chunk * 8 + srow;
      gload16(Abase + (size_t)(m0 + row) * lda + kloc + scol, &As[buf][chunk * 512]);
      gload16(Bbase + (size_t)(n0 + row) * ldb + k0 + scol,   &Bs[buf][chunk * 512]);
    }
  };

  stage(0, 0);
  __syncthreads();                               // drains vmcnt(0): buf0 resident
  for (int t = 0; t < nt; ++t) {
    const int cur = t & 1;
    if (t + 1 < nt) stage(cur ^ 1, (t + 1) * 64);   // prefetch BEFORE compute
    #pragma unroll
    for (int kk = 0; kk < 64; kk += 32) {
      s16x8 af[8], bfr[4];
      #pragma unroll
      for (int mi = 0; mi < 8; ++mi)
        af[mi] = *reinterpret_cast<const s16x8*>(
            &As[cur][(wr * 128 + mi * 16 + l15) * 64 + kk + l4 * 8]);
      #pragma unroll
      for (int ni = 0; ni < 4; ++ni)
        bfr[ni] = *reinterpret_cast<const s16x8*>(
            &Bs[cur][(wc * 64 + ni * 16 + l15) * 64 + kk + l4 * 8]);
      #pragma unroll
      for (int mi = 0; mi < 8; ++mi)
        #pragma unroll
        for (int ni = 0; ni < 4; ++ni)
          acc[mi][ni] = mfma16(af[mi], bfr[ni], acc[mi][ni]);
    }
    __syncthreads();   // drains this wave's stage vmcnt (hidden under compute) + barrier
  }

  #pragma unroll
  for (int mi = 0; mi < 8; ++mi) {
    #pragma unroll
    for (int ni = 0; ni < 4; ++ni) {
      int col = n0 + wc * 64 + ni * 16 + l15;
      #pragma unroll
      for (int j = 0; j < 4; ++j) {
        int row = m0 + wr * 128 + mi * 16 + l4 * 4 + j;
        float v = acc[mi][ni][j];
        size_t cidx = Coff + (size_t)row * N + col;
        if (EPI == 0) {
          Cb[cidx] = f2bf(fmaxf(v, 0.f));
        } else if (EPI == 1) {
          Cf[cidx] = v;
        } else {
          float r = (col < Ksplit) ? R0[(size_t)row * 512 + col]
                                   : bf2f(R1[(size_t)row * 512 + (col - 512)]);
          float g = 1.0f / (1.0f + __expf(-v));
          Cf[cidx] = r * g;
        }
      }
    }
  }
}

// ======== P @ memory, 128x128 tile, dbuf prefetch, XCD-swizzled grid ========
// P: [8][2048] rows, row stride 4096 u16 (first 2048 cols valid, bf16)
// MT: [8][512][2048] bf16 (memory^T), C: [8][2048][512] bf16
__global__ __launch_bounds__(256) void gemm_pm_k(const u16* __restrict__ P,
                                                 const u16* __restrict__ MT,
                                                 u16* __restrict__ C) {
  __shared__ u16 As[2][128 * 64];
  __shared__ u16 Bs[2][128 * 64];
  // 512 blocks; cluster the 4 n-blocks of each (m,z) panel onto one XCD
  const int l = blockIdx.x;
  const int logical = (l & 7) * 64 + (l >> 3);
  const int n0 = (logical & 3) * 128;
  const int m0 = ((logical >> 2) & 15) * 128;
  const int z = logical >> 6;
  const u16* Ab = P + (size_t)z * 2048 * 4096;
  const u16* Bb = MT + (size_t)z * 512 * 2048;
  u16* Cb = C + (size_t)z * 2048 * 512;
  const int tid = threadIdx.x, wave = tid >> 6, lane = tid & 63;
  const int wr = wave >> 1, wc = wave & 1;
  const int l15 = lane & 15, l4 = lane >> 4;
  const int srow = lane >> 3, scol = (lane & 7) * 8;

  f32x4 acc[4][4];
  #pragma unroll
  for (int i = 0; i < 4; ++i)
    #pragma unroll
    for (int j = 0; j < 4; ++j) acc[i][j] = (f32x4){0.f, 0.f, 0.f, 0.f};

  auto stage = [&](int buf, int k0) {
    #pragma unroll
    for (int c = 0; c < 4; ++c) {
      int chunk = wave * 4 + c;                 // 0..15
      int row = chunk * 8 + srow;
      gload16(Ab + (size_t)(m0 + row) * 4096 + k0 + scol, &As[buf][chunk * 512]);
      gload16(Bb + (size_t)(n0 + row) * 2048 + k0 + scol, &Bs[buf][chunk * 512]);
    }
  };

  stage(0, 0);
  __syncthreads();
  for (int t = 0; t < 32; ++t) {
    const int cur = t & 1;
    if (t < 31) stage(cur ^ 1, (t + 1) * 64);
    #pragma unroll
    for (int kk = 0; kk < 64; kk += 32) {
      s16x8 af[4], bfr[4];
      #pragma unroll
      for (int mi = 0; mi < 4; ++mi)
        af[mi] = *reinterpret_cast<const s16x8*>(
            &As[cur][(wr * 64 + mi * 16 + l15) * 64 + kk + l4 * 8]);
      #pragma unroll
      for (int ni = 0; ni < 4; ++ni)
        bfr[ni] = *reinterpret_cast<const s16x8*>(
            &Bs[cur][(wc * 64 + ni * 16 + l15) * 64 + kk + l4 * 8]);
      #pragma unroll
      for (int mi = 0; mi < 4; ++mi)
        #pragma unroll
        for (int ni = 0; ni < 4; ++ni)
          acc[mi][ni] = mfma16(af[mi], bfr[ni], acc[mi][ni]);
    }
    __syncthreads();
  }

  #pragma unroll
  for (int mi = 0; mi < 4; ++mi) {
    #pragma unroll
    for (int ni = 0; ni < 4; ++ni) {
      int col = n0 + wc * 64 + ni * 16 + l15;
      #pragma unroll
      for (int j = 0; j < 4; ++j) {
        int row = m0 + wr * 64 + mi * 16 + l4 * 4 + j;
        Cb[(size_t)row * 512 + col] = f2bf(acc[mi][ni][j]);
      }
    }
  }
}

extern "C" void kernel_launch(void* const* d_in, const int* in_sizes, int n_in,
                              void* d_out, int out_size, void* d_ws, size_t ws_size,
                              hipStream_t stream) {
  const float* inputs = (const float*)d_in[0];  // [8,2048,512]
  const float* memory = (const float*)d_in[1];  // [8,2048,512]
  const int*   mask   = (const int*)d_in[2];    // [8,2048]
  const float* Wq     = (const float*)d_in[3];  // [512,512]
  const float* Wk     = (const float*)d_in[4];  // [512,512]
  const float* Wg     = (const float*)d_in[5];  // [1024,1024]
  float* out = (float*)d_out;                   // [8,2048,1024]

  char* ws = (char*)d_ws;
  size_t off = 0;
  auto alloc = [&](size_t bytes) {
    void* p = ws + off;
    off += (bytes + 255) & ~(size_t)255;
    return p;
  };
  u16* in_b  = (u16*)alloc(16384ULL * 512 * 2);   // inputs bf16   } contiguous
  u16* mem_b = (u16*)alloc(16384ULL * 512 * 2);   // memory bf16   } pair
  u16* memT  = (u16*)alloc(16384ULL * 512 * 2);   // memory^T bf16 [B][512][2048]
  u16* WqT   = (u16*)alloc(512ULL * 512 * 2);
  u16* WkT   = (u16*)alloc(512ULL * 512 * 2);
  u16* WgT   = (u16*)alloc(1024ULL * 1024 * 2);
  u16* q_b   = (u16*)alloc(16384ULL * 512 * 2);   // } contiguous pair
  u16* k_b   = (u16*)alloc(16384ULL * 512 * 2);   // }
  float* sc  = (float*)alloc(8ULL * 2048 * 2048 * 4);  // scores f32 -> P bf16 in-place
  u16* att_b = (u16*)alloc(16384ULL * 512 * 2);
  (void)ws_size; (void)in_sizes; (void)n_in; (void)out_size;

  const int n8 = (16384 * 512) / 8;
  cvt_k<<<(n8 + 255) / 256, 256, 0, stream>>>(inputs, in_b, n8);
  cvt_k<<<(n8 + 255) / 256, 256, 0, stream>>>(memory, mem_b, n8);
  dim3 tb(32, 8);
  tcvt_k<<<dim3(16, 16, 1), tb, 0, stream>>>(Wq, WqT, 512, 512, 0, 0);
  tcvt_k<<<dim3(16, 16, 1), tb, 0, stream>>>(Wk, WkT, 512, 512, 0, 0);
  tcvt_k<<<dim3(32, 32, 1), tb, 0, stream>>>(Wg, WgT, 1024, 1024, 0, 0);
  tcvt_k<<<dim3(16, 64, 8), tb, 0, stream>>>(memory, memT, 2048, 512,
                                             2048LL * 512, 2048LL * 512);

  // [q|k] = relu([inputs|memory] @ [Wq or Wk])  — one M=32768 launch
  gemm256_k<0><<<dim3(2, 128, 1), 512, 0, stream>>>(
      in_b, nullptr, WqT, WkT, nullptr, q_b, nullptr, nullptr,
      32768, 512, 512, 512, 512, 512, 16384, 0, 0, 0);

  // scores[b] = q[b] @ k[b]^T  (raw f32; scale+mask in softmax)
  gemm256_k<1><<<dim3(8, 8, 8), 512, 0, stream>>>(
      q_b, nullptr, k_b, k_b, sc, nullptr, nullptr, nullptr,
      2048, 2048, 512, 512, 512, 512, 1 << 30,
      2048LL * 512, 2048LL * 512, 2048LL * 2048);

  // masked scaled softmax, bf16 P in place (row stride 4096 u16)
  softmax_k<<<16384, 256, 0, stream>>>(sc, mask, (u16*)sc, 0.044194173824159216f);

  // att[b] = P[b] @ memory[b] -> bf16
  gemm_pm_k<<<512, 256, 0, stream>>>((const u16*)sc, memT, att_b);

  // out = res * sigmoid(res @ Wg), res = [inputs | att]
  gemm256_k<3><<<dim3(4, 64, 1), 512, 0, stream>>>(
      in_b, att_b, WgT, WgT, out, nullptr, inputs, att_b,
      16384, 1024, 1024, 512, 1024, 512, 1 << 30, 0, 0, 0);
}

// Round 4
// 313.064 us; speedup vs baseline: 1.1250x; 1.1250x over previous
//
#include <hip/hip_runtime.h>

typedef unsigned short u16;
typedef unsigned int   u32;

typedef short s16x8 __attribute__((ext_vector_type(8)));
typedef float f32x4 __attribute__((ext_vector_type(4)));

static __device__ __forceinline__ u16 f2bf(float f) {
  u32 u = __float_as_uint(f);
  u = (u + 0x7fffu + ((u >> 16) & 1u)) >> 16;
  return (u16)u;
}
static __device__ __forceinline__ float bf2f(u16 h) {
  return __uint_as_float(((u32)h) << 16);
}
static __device__ __forceinline__ f32x4 mfma16(s16x8 a, s16x8 b, f32x4 c) {
  return __builtin_amdgcn_mfma_f32_16x16x32_bf16(a, b, c, 0, 0, 0);
}
static __device__ __forceinline__ void gload16(const u16* g, u16* l) {
  __builtin_amdgcn_global_load_lds(
      (const __attribute__((address_space(1))) void*)g,
      (__attribute__((address_space(3))) void*)l, 16, 0, 0);
}

#define WAITVM8() asm volatile("s_waitcnt vmcnt(8)" ::: "memory")
#define WAITVM0() asm volatile("s_waitcnt vmcnt(0)" ::: "memory")
#define BAR()                                  \
  do {                                         \
    asm volatile("" ::: "memory");             \
    __builtin_amdgcn_s_barrier();              \
    asm volatile("" ::: "memory");             \
  } while (0)

// ---------------- flat f32 -> bf16 convert, 8 elems/thread ----------------
__global__ __launch_bounds__(256) void cvt_k(const float* __restrict__ in,
                                             u16* __restrict__ out, int n8) {
  int i = blockIdx.x * 256 + threadIdx.x;
  if (i >= n8) return;
  const float4* p = reinterpret_cast<const float4*>(in);
  float4 a = p[2 * i], b = p[2 * i + 1];
  union { u16 u[8]; uint4 v; } r;
  r.u[0] = f2bf(a.x); r.u[1] = f2bf(a.y); r.u[2] = f2bf(a.z); r.u[3] = f2bf(a.w);
  r.u[4] = f2bf(b.x); r.u[5] = f2bf(b.y); r.u[6] = f2bf(b.z); r.u[7] = f2bf(b.w);
  reinterpret_cast<uint4*>(out)[i] = r.v;
}

// ------------- transpose+convert: in [R,C] f32 -> out [C,R] bf16, batched -------------
__global__ void tcvt_k(const float* __restrict__ in, u16* __restrict__ out,
                       int R, int C, long long ibs, long long obs) {
  __shared__ float t[32][33];
  const float* ip = in + (size_t)blockIdx.z * ibs;
  u16* op = out + (size_t)blockIdx.z * obs;
  int r0 = blockIdx.y * 32, c0 = blockIdx.x * 32;
  int x = threadIdx.x, y = threadIdx.y;
  for (int i = y; i < 32; i += 8) t[i][x] = ip[(size_t)(r0 + i) * C + c0 + x];
  __syncthreads();
  for (int i = y; i < 32; i += 8) op[(size_t)(c0 + i) * R + r0 + x] = f2bf(t[x][i]);
}

// ------------- row softmax with mask, in-place f32 -> bf16 (row-local) -------------
__global__ __launch_bounds__(256) void softmax_k(const float* __restrict__ S,
                                                 const int* __restrict__ mask,
                                                 u16* __restrict__ P, float scale) {
  __shared__ float redm[4], reds[4];
  const int row = blockIdx.x;
  const int bb = row >> 11;
  const int tid = threadIdx.x;
  const float* s = S + (size_t)row * 2048;
  const int* mk = mask + (size_t)bb * 2048;
  float4 a = reinterpret_cast<const float4*>(s)[2 * tid];
  float4 c = reinterpret_cast<const float4*>(s)[2 * tid + 1];
  int4 ma = reinterpret_cast<const int4*>(mk)[2 * tid];
  int4 mc = reinterpret_cast<const int4*>(mk)[2 * tid + 1];
  float v[8];
  v[0] = ma.x ? a.x * scale : -1e30f;
  v[1] = ma.y ? a.y * scale : -1e30f;
  v[2] = ma.z ? a.z * scale : -1e30f;
  v[3] = ma.w ? a.w * scale : -1e30f;
  v[4] = mc.x ? c.x * scale : -1e30f;
  v[5] = mc.y ? c.y * scale : -1e30f;
  v[6] = mc.z ? c.z * scale : -1e30f;
  v[7] = mc.w ? c.w * scale : -1e30f;
  float mx = v[0];
  #pragma unroll
  for (int i = 1; i < 8; ++i) mx = fmaxf(mx, v[i]);
  for (int off = 32; off; off >>= 1) mx = fmaxf(mx, __shfl_xor(mx, off));
  if ((tid & 63) == 0) redm[tid >> 6] = mx;
  __syncthreads();
  mx = fmaxf(fmaxf(redm[0], redm[1]), fmaxf(redm[2], redm[3]));
  float sum = 0.f;
  #pragma unroll
  for (int i = 0; i < 8; ++i) { v[i] = __expf(v[i] - mx); sum += v[i]; }
  for (int off = 32; off; off >>= 1) sum += __shfl_xor(sum, off);
  if ((tid & 63) == 0) reds[tid >> 6] = sum;
  __syncthreads();
  sum = reds[0] + reds[1] + reds[2] + reds[3];
  float inv = 1.0f / sum;
  union { u16 u[8]; uint4 q; } r;
  #pragma unroll
  for (int i = 0; i < 8; ++i) r.u[i] = f2bf(v[i] * inv);
  reinterpret_cast<uint4*>(P + (size_t)row * 4096)[tid] = r.q;
}

// ======== 256x256-tile, 8-wave, counted-vmcnt dbuf, T2-swizzled bf16 GEMM ========
// A:[*,K](lda) bf16; K-split A/A2 at Ksplit. Bt:[N,K](ldb); M-split Bt/Bt2 at Msp.
// 1-D grid nwg blocks, XCD-chunked remap; decode (bx,by,bz) from nx,ny.
// EPI 0: relu->bf16 Cb | 1: f32 Cf | 3: gate(R0/R1, sigmoid, f32 Cf)
template <int EPI>
__global__ __launch_bounds__(512, 2) void gemm256_k(
    const u16* __restrict__ A, const u16* __restrict__ A2,
    const u16* __restrict__ Bt, const u16* __restrict__ Bt2,
    float* __restrict__ Cf, u16* __restrict__ Cb,
    const float* __restrict__ R0, const u16* __restrict__ R1,
    int N, int K, int lda, int ldb, int Ksplit, int Msp,
    int nx, int ny, int nwg,
    long long A_bs, long long B_bs, long long C_bs) {
  __shared__ u16 As[2][256 * 64];
  __shared__ u16 Bs[2][256 * 64];
  const int bid = blockIdx.x;
  const int wgid = (bid & 7) * (nwg >> 3) + (bid >> 3);   // XCD-chunked (nwg%8==0)
  const int bx = wgid % nx;
  const int by = (wgid / nx) % ny;
  const int bz = wgid / (nx * ny);
  const int tid = threadIdx.x;
  const int wave = tid >> 6, lane = tid & 63;
  const size_t Aoff = (size_t)bz * A_bs;
  const size_t Boff = (size_t)bz * B_bs;
  const size_t Coff = (size_t)bz * C_bs;
  const int m0 = by * 256, n0 = bx * 256;
  const int wr = wave >> 2, wc = wave & 3;      // 2 x 4 waves, each owns 128x64
  const int l15 = lane & 15, l4 = lane >> 4;
  const int srow = lane >> 3;                   // 0..7 within 8-row chunk
  const int scolsw = (((lane & 7) ^ (lane >> 3)) << 3);  // T2 pre-swizzled source col (u16)
  const int rsw = (l15 & 7) << 3;               // read-side XOR (u16)
  const u16* Bbase = ((m0 < Msp) ? Bt : Bt2) + Boff;

  f32x4 acc[8][4];
  #pragma unroll
  for (int i = 0; i < 8; ++i)
    #pragma unroll
    for (int j = 0; j < 4; ++j) acc[i][j] = (f32x4){0.f, 0.f, 0.f, 0.f};

  const int nt = K / 64;
  auto stage = [&](int buf, int k0) {
    const u16* Abase; int kloc;
    if (k0 < Ksplit) { Abase = A + Aoff;  kloc = k0; }
    else             { Abase = A2 + Aoff; kloc = k0 - Ksplit; }
    #pragma unroll
    for (int c = 0; c < 4; ++c) {
      int chunk = wave * 4 + c;                 // 0..31, 1KB each (8 rows x 128B)
      int row = chunk * 8 + srow;
      gload16(Abase + (size_t)(m0 + row) * lda + kloc + scolsw, &As[buf][chunk * 512]);
      gload16(Bbase + (size_t)(n0 + row) * ldb + k0 + scolsw,   &Bs[buf][chunk * 512]);
    }
  };
  auto compute = [&](int cur) {
    __builtin_amdgcn_s_setprio(1);
    #pragma unroll
    for (int kk = 0; kk < 64; kk += 32) {
      s16x8 af[8], bfr[4];
      #pragma unroll
      for (int mi = 0; mi < 8; ++mi)
        af[mi] = *reinterpret_cast<const s16x8*>(
            &As[cur][(wr * 128 + mi * 16 + l15) * 64 + (((kk + l4 * 8) ^ rsw))]);
      #pragma unroll
      for (int ni = 0; ni < 4; ++ni)
        bfr[ni] = *reinterpret_cast<const s16x8*>(
            &Bs[cur][(wc * 64 + ni * 16 + l15) * 64 + (((kk + l4 * 8) ^ rsw))]);
      #pragma unroll
      for (int mi = 0; mi < 8; ++mi)
        #pragma unroll
        for (int ni = 0; ni < 4; ++ni)
          acc[mi][ni] = mfma16(af[mi], bfr[ni], acc[mi][ni]);
    }
    __builtin_amdgcn_s_setprio(0);
  };

  // prologue: tile0 + tile1 in flight; wait only tile0
  stage(0, 0);
  if (nt > 1) { stage(1, 64); WAITVM8(); } else { WAITVM0(); }
  BAR();
  for (int t = 0; t < nt; ++t) {
    const int cur = t & 1;
    compute(cur);
    BAR();                                   // WAR: all waves done reading buf[cur]
    if (t + 2 < nt) stage(cur, (t + 2) * 64);
    if (t + 1 < nt) {
      if (t + 2 < nt) { WAITVM8(); } else { WAITVM0(); }  // tile t+1 resident
      BAR();                                 // RAW: visible to all waves
    }
  }

  #pragma unroll
  for (int mi = 0; mi < 8; ++mi) {
    #pragma unroll
    for (int ni = 0; ni < 4; ++ni) {
      int col = n0 + wc * 64 + ni * 16 + l15;
      #pragma unroll
      for (int j = 0; j < 4; ++j) {
        int row = m0 + wr * 128 + mi * 16 + l4 * 4 + j;
        float v = acc[mi][ni][j];
        size_t cidx = Coff + (size_t)row * N + col;
        if (EPI == 0) {
          Cb[cidx] = f2bf(fmaxf(v, 0.f));
        } else if (EPI == 1) {
          Cf[cidx] = v;
        } else {
          float r = (col < Ksplit) ? R0[(size_t)row * 512 + col]
                                   : bf2f(R1[(size_t)row * 512 + (col - 512)]);
          float g = 1.0f / (1.0f + __expf(-v));
          Cf[cidx] = r * g;
        }
      }
    }
  }
}

// ======== P @ memory, 128x128 tile, counted-vmcnt dbuf, T2 swizzle, XCD remap ========
// P: [8][2048] rows, row stride 4096 u16 (first 2048 bf16 valid)
// MT: [8][512][2048] bf16, C: [8][2048][512] bf16
__global__ __launch_bounds__(256, 2) void gemm_pm_k(const u16* __restrict__ P,
                                                    const u16* __restrict__ MT,
                                                    u16* __restrict__ C) {
  __shared__ u16 As[2][128 * 64];
  __shared__ u16 Bs[2][128 * 64];
  const int l = blockIdx.x;
  const int logical = (l & 7) * 64 + (l >> 3);   // XCD-chunked over 512 blocks
  const int n0 = (logical & 3) * 128;
  const int m0 = ((logical >> 2) & 15) * 128;
  const int z = logical >> 6;
  const u16* Ab = P + (size_t)z * 2048 * 4096;
  const u16* Bb = MT + (size_t)z * 512 * 2048;
  u16* Cb = C + (size_t)z * 2048 * 512;
  const int tid = threadIdx.x, wave = tid >> 6, lane = tid & 63;
  const int wr = wave >> 1, wc = wave & 1;
  const int l15 = lane & 15, l4 = lane >> 4;
  const int srow = lane >> 3;
  const int scolsw = (((lane & 7) ^ (lane >> 3)) << 3);
  const int rsw = (l15 & 7) << 3;

  f32x4 acc[4][4];
  #pragma unroll
  for (int i = 0; i < 4; ++i)
    #pragma unroll
    for (int j = 0; j < 4; ++j) acc[i][j] = (f32x4){0.f, 0.f, 0.f, 0.f};

  auto stage = [&](int buf, int k0) {
    #pragma unroll
    for (int c = 0; c < 4; ++c) {
      int chunk = wave * 4 + c;                 // 0..15
      int row = chunk * 8 + srow;
      gload16(Ab + (size_t)(m0 + row) * 4096 + k0 + scolsw, &As[buf][chunk * 512]);
      gload16(Bb + (size_t)(n0 + row) * 2048 + k0 + scolsw, &Bs[buf][chunk * 512]);
    }
  };
  auto compute = [&](int cur) {
    __builtin_amdgcn_s_setprio(1);
    #pragma unroll
    for (int kk = 0; kk < 64; kk += 32) {
      s16x8 af[4], bfr[4];
      #pragma unroll
      for (int mi = 0; mi < 4; ++mi)
        af[mi] = *reinterpret_cast<const s16x8*>(
            &As[cur][(wr * 64 + mi * 16 + l15) * 64 + (((kk + l4 * 8) ^ rsw))]);
      #pragma unroll
      for (int ni = 0; ni < 4; ++ni)
        bfr[ni] = *reinterpret_cast<const s16x8*>(
            &Bs[cur][(wc * 64 + ni * 16 + l15) * 64 + (((kk + l4 * 8) ^ rsw))]);
      #pragma unroll
      for (int mi = 0; mi < 4; ++mi)
        #pragma unroll
        for (int ni = 0; ni < 4; ++ni)
          acc[mi][ni] = mfma16(af[mi], bfr[ni], acc[mi][ni]);
    }
    __builtin_amdgcn_s_setprio(0);
  };

  const int nt = 32;
  stage(0, 0);
  stage(1, 64);
  WAITVM8();
  BAR();
  for (int t = 0; t < nt; ++t) {
    const int cur = t & 1;
    compute(cur);
    BAR();
    if (t + 2 < nt) stage(cur, (t + 2) * 64);
    if (t + 1 < nt) {
      if (t + 2 < nt) { WAITVM8(); } else { WAITVM0(); }
      BAR();
    }
  }

  #pragma unroll
  for (int mi = 0; mi < 4; ++mi) {
    #pragma unroll
    for (int ni = 0; ni < 4; ++ni) {
      int col = n0 + wc * 64 + ni * 16 + l15;
      #pragma unroll
      for (int j = 0; j < 4; ++j) {
        int row = m0 + wr * 64 + mi * 16 + l4 * 4 + j;
        Cb[(size_t)row * 512 + col] = f2bf(acc[mi][ni][j]);
      }
    }
  }
}

extern "C" void kernel_launch(void* const* d_in, const int* in_sizes, int n_in,
                              void* d_out, int out_size, void* d_ws, size_t ws_size,
                              hipStream_t stream) {
  const float* inputs = (const float*)d_in[0];  // [8,2048,512]
  const float* memory = (const float*)d_in[1];  // [8,2048,512]
  const int*   mask   = (const int*)d_in[2];    // [8,2048]
  const float* Wq     = (const float*)d_in[3];  // [512,512]
  const float* Wk     = (const float*)d_in[4];  // [512,512]
  const float* Wg     = (const float*)d_in[5];  // [1024,1024]
  float* out = (float*)d_out;                   // [8,2048,1024]

  char* ws = (char*)d_ws;
  size_t off = 0;
  auto alloc = [&](size_t bytes) {
    void* p = ws + off;
    off += (bytes + 255) & ~(size_t)255;
    return p;
  };
  u16* in_b  = (u16*)alloc(16384ULL * 512 * 2);   // inputs bf16   } contiguous
  u16* mem_b = (u16*)alloc(16384ULL * 512 * 2);   // memory bf16   } pair
  u16* memT  = (u16*)alloc(16384ULL * 512 * 2);   // memory^T bf16 [B][512][2048]
  u16* WqT   = (u16*)alloc(512ULL * 512 * 2);
  u16* WkT   = (u16*)alloc(512ULL * 512 * 2);
  u16* WgT   = (u16*)alloc(1024ULL * 1024 * 2);
  u16* q_b   = (u16*)alloc(16384ULL * 512 * 2);   // } contiguous pair
  u16* k_b   = (u16*)alloc(16384ULL * 512 * 2);   // }
  float* sc  = (float*)alloc(8ULL * 2048 * 2048 * 4);  // scores f32 -> P bf16 in-place
  u16* att_b = (u16*)alloc(16384ULL * 512 * 2);
  (void)ws_size; (void)in_sizes; (void)n_in; (void)out_size;

  const int n8 = (16384 * 512) / 8;
  cvt_k<<<(n8 + 255) / 256, 256, 0, stream>>>(inputs, in_b, n8);
  cvt_k<<<(n8 + 255) / 256, 256, 0, stream>>>(memory, mem_b, n8);
  dim3 tb(32, 8);
  tcvt_k<<<dim3(16, 16, 1), tb, 0, stream>>>(Wq, WqT, 512, 512, 0, 0);
  tcvt_k<<<dim3(16, 16, 1), tb, 0, stream>>>(Wk, WkT, 512, 512, 0, 0);
  tcvt_k<<<dim3(32, 32, 1), tb, 0, stream>>>(Wg, WgT, 1024, 1024, 0, 0);
  tcvt_k<<<dim3(16, 64, 8), tb, 0, stream>>>(memory, memT, 2048, 512,
                                             2048LL * 512, 2048LL * 512);

  // [q|k] = relu([inputs|memory] @ [Wq or Wk])  — one M=32768 launch, 256 blocks
  gemm256_k<0><<<256, 512, 0, stream>>>(
      in_b, nullptr, WqT, WkT, nullptr, q_b, nullptr, nullptr,
      512, 512, 512, 512, 1 << 30, 16384, 2, 128, 256, 0, 0, 0);

  // scores[b] = q[b] @ k[b]^T  (raw f32; scale+mask in softmax), 512 blocks
  gemm256_k<1><<<512, 512, 0, stream>>>(
      q_b, nullptr, k_b, k_b, sc, nullptr, nullptr, nullptr,
      2048, 512, 512, 512, 1 << 30, 1 << 30, 8, 8, 512,
      2048LL * 512, 2048LL * 512, 2048LL * 2048);

  // masked scaled softmax, bf16 P in place (row stride 4096 u16)
  softmax_k<<<16384, 256, 0, stream>>>(sc, mask, (u16*)sc, 0.044194173824159216f);

  // att[b] = P[b] @ memory[b] -> bf16, 512 blocks
  gemm_pm_k<<<512, 256, 0, stream>>>((const u16*)sc, memT, att_b);

  // out = res * sigmoid(res @ Wg), res = [inputs | att], 256 blocks
  gemm256_k<3><<<256, 512, 0, stream>>>(
      in_b, att_b, WgT, WgT, out, nullptr, inputs, att_b,
      1024, 1024, 512, 1024, 512, 1 << 30, 4, 64, 256, 0, 0, 0);
}

// Round 5
// 280.779 us; speedup vs baseline: 1.2544x; 1.1150x over previous
//
#include <hip/hip_runtime.h>

typedef unsigned short u16;
typedef unsigned int   u32;

typedef short s16x8 __attribute__((ext_vector_type(8)));
typedef float f32x4 __attribute__((ext_vector_type(4)));

static __device__ __forceinline__ u16 f2bf(float f) {
  u32 u = __float_as_uint(f);
  u = (u + 0x7fffu + ((u >> 16) & 1u)) >> 16;
  return (u16)u;
}
static __device__ __forceinline__ float bf2f(u16 h) {
  return __uint_as_float(((u32)h) << 16);
}
static __device__ __forceinline__ f32x4 mfma16(s16x8 a, s16x8 b, f32x4 c) {
  return __builtin_amdgcn_mfma_f32_16x16x32_bf16(a, b, c, 0, 0, 0);
}
static __device__ __forceinline__ void gload16(const u16* g, u16* l) {
  __builtin_amdgcn_global_load_lds(
      (const __attribute__((address_space(1))) void*)g,
      (__attribute__((address_space(3))) void*)l, 16, 0, 0);
}

#define WAITVM0() asm volatile("s_waitcnt vmcnt(0)" ::: "memory")
#define BAR()                                  \
  do {                                         \
    asm volatile("" ::: "memory");             \
    __builtin_amdgcn_s_barrier();              \
    asm volatile("" ::: "memory");             \
  } while (0)

// ---------------- flat f32 -> bf16 convert, 8 elems/thread ----------------
__global__ __launch_bounds__(256) void cvt_k(const float* __restrict__ in,
                                             u16* __restrict__ out, int n8) {
  int i = blockIdx.x * 256 + threadIdx.x;
  if (i >= n8) return;
  const float4* p = reinterpret_cast<const float4*>(in);
  float4 a = p[2 * i], b = p[2 * i + 1];
  union { u16 u[8]; uint4 v; } r;
  r.u[0] = f2bf(a.x); r.u[1] = f2bf(a.y); r.u[2] = f2bf(a.z); r.u[3] = f2bf(a.w);
  r.u[4] = f2bf(b.x); r.u[5] = f2bf(b.y); r.u[6] = f2bf(b.z); r.u[7] = f2bf(b.w);
  reinterpret_cast<uint4*>(out)[i] = r.v;
}

// ------------- transpose+convert: in [R,C] f32 -> out [C,R] bf16, batched -------------
__global__ void tcvt_k(const float* __restrict__ in, u16* __restrict__ out,
                       int R, int C, long long ibs, long long obs) {
  __shared__ float t[32][33];
  const float* ip = in + (size_t)blockIdx.z * ibs;
  u16* op = out + (size_t)blockIdx.z * obs;
  int r0 = blockIdx.y * 32, c0 = blockIdx.x * 32;
  int x = threadIdx.x, y = threadIdx.y;
  for (int i = y; i < 32; i += 8) t[i][x] = ip[(size_t)(r0 + i) * C + c0 + x];
  __syncthreads();
  for (int i = y; i < 32; i += 8) op[(size_t)(c0 + i) * R + r0 + x] = f2bf(t[x][i]);
}

// ------------- row softmax with mask, bf16 in-place (row stride 4096 u16) -------------
__global__ __launch_bounds__(256) void softmax_k(u16* __restrict__ P,
                                                 const int* __restrict__ mask,
                                                 float scale) {
  __shared__ float redm[4], reds[4];
  const int row = blockIdx.x;
  const int bb = row >> 11;
  const int tid = threadIdx.x;
  u16* p = P + (size_t)row * 4096;
  const int* mk = mask + (size_t)bb * 2048;
  uint4 raw = reinterpret_cast<const uint4*>(p)[tid];
  int4 ma = reinterpret_cast<const int4*>(mk)[2 * tid];
  int4 mc = reinterpret_cast<const int4*>(mk)[2 * tid + 1];
  float v[8];
  v[0] = ma.x ? bf2f((u16)(raw.x & 0xffff)) * scale : -1e30f;
  v[1] = ma.y ? bf2f((u16)(raw.x >> 16))    * scale : -1e30f;
  v[2] = ma.z ? bf2f((u16)(raw.y & 0xffff)) * scale : -1e30f;
  v[3] = ma.w ? bf2f((u16)(raw.y >> 16))    * scale : -1e30f;
  v[4] = mc.x ? bf2f((u16)(raw.z & 0xffff)) * scale : -1e30f;
  v[5] = mc.y ? bf2f((u16)(raw.z >> 16))    * scale : -1e30f;
  v[6] = mc.z ? bf2f((u16)(raw.w & 0xffff)) * scale : -1e30f;
  v[7] = mc.w ? bf2f((u16)(raw.w >> 16))    * scale : -1e30f;
  float mx = v[0];
  #pragma unroll
  for (int i = 1; i < 8; ++i) mx = fmaxf(mx, v[i]);
  for (int off = 32; off; off >>= 1) mx = fmaxf(mx, __shfl_xor(mx, off));
  if ((tid & 63) == 0) redm[tid >> 6] = mx;
  __syncthreads();
  mx = fmaxf(fmaxf(redm[0], redm[1]), fmaxf(redm[2], redm[3]));
  float sum = 0.f;
  #pragma unroll
  for (int i = 0; i < 8; ++i) { v[i] = __expf(v[i] - mx); sum += v[i]; }
  for (int off = 32; off; off >>= 1) sum += __shfl_xor(sum, off);
  if ((tid & 63) == 0) reds[tid >> 6] = sum;
  __syncthreads();
  sum = reds[0] + reds[1] + reds[2] + reds[3];
  float inv = 1.0f / sum;
  union { u16 u[8]; uint4 q; } r;
  #pragma unroll
  for (int i = 0; i < 8; ++i) r.u[i] = f2bf(v[i] * inv);
  reinterpret_cast<uint4*>(p)[tid] = r.q;
}

// ======== 256x256-tile, 8-wave, 8-phase (4 phases/K-tile) bf16 GEMM ========
// A:[*,K](lda) bf16; K-split A/A2 at Ksplit. Bt:[N,K](ldb); M-split Bt/Bt2 at Msp.
// 1-D grid, XCD-chunked remap. EPI 0: relu->bf16 Cb(ldc) | 1: bf16 Cb(ldc) |
// 3: gate (R0 f32 / R1 bf16, sigmoid, f32 Cf(ldc))
template <int EPI>
__global__ __launch_bounds__(512, 2) void gemm8p_k(
    const u16* __restrict__ A, const u16* __restrict__ A2,
    const u16* __restrict__ Bt, const u16* __restrict__ Bt2,
    float* __restrict__ Cf, u16* __restrict__ Cb,
    const float* __restrict__ R0, const u16* __restrict__ R1,
    int N, int K, int lda, int ldb, int ldc, int Ksplit, int Msp,
    int nx, int ny, int nwg,
    long long A_bs, long long B_bs, long long C_bs) {
  __shared__ u16 As[2][256 * 64];
  __shared__ u16 Bs[2][256 * 64];
  const int bid = blockIdx.x;
  const int wgid = (bid & 7) * (nwg >> 3) + (bid >> 3);   // XCD-chunked (nwg%8==0)
  const int bx = wgid % nx;
  const int by = (wgid / nx) % ny;
  const int bz = wgid / (nx * ny);
  const int tid = threadIdx.x;
  const int wave = tid >> 6, lane = tid & 63;
  const size_t Aoff = (size_t)bz * A_bs;
  const size_t Boff = (size_t)bz * B_bs;
  const size_t Coff = (size_t)bz * C_bs;
  const int m0 = by * 256, n0 = bx * 256;
  const int wr = wave >> 2, wc = wave & 3;      // 2 x 4 waves, each owns 128x64
  const int l15 = lane & 15, l4 = lane >> 4;
  const int srow = lane >> 3;                   // 0..7 within 8-row chunk
  const int scolsw = (((lane & 7) ^ (lane >> 3)) << 3);  // T2 pre-swizzled src col
  const int rsw = (l15 & 7) << 3;               // read-side XOR (u16 elems)
  const u16* Bbase = ((m0 < Msp) ? Bt : Bt2) + Boff;

  f32x4 acc[8][4];
  #pragma unroll
  for (int i = 0; i < 8; ++i)
    #pragma unroll
    for (int j = 0; j < 4; ++j) acc[i][j] = (f32x4){0.f, 0.f, 0.f, 0.f};

  const int nt = K / 64;
  auto stageTile = [&](int buf, int k0) {       // 8 gloads/wave, whole 256x64 A+B
    const u16* Abase; int kloc;
    if (k0 < Ksplit) { Abase = A + Aoff;  kloc = k0; }
    else             { Abase = A2 + Aoff; kloc = k0 - Ksplit; }
    #pragma unroll
    for (int c = 0; c < 4; ++c) {
      int chunk = wave * 4 + c;                 // 0..31, 1KB each (8 rows x 128B)
      int row = chunk * 8 + srow;
      gload16(Abase + (size_t)(m0 + row) * lda + kloc + scolsw, &As[buf][chunk * 512]);
      gload16(Bbase + (size_t)(n0 + row) * ldb + k0 + scolsw,   &Bs[buf][chunk * 512]);
    }
  };

  // prologue: tile 0 resident
  stageTile(0, 0);
  WAITVM0();
  BAR();

  for (int t = 0; t < nt; ++t) {
    const int b = t & 1;
    if (t + 1 < nt) stageTile(b ^ 1, (t + 1) * 64);   // in flight across all phases
    // B-fragments for the whole K-tile (8 ds_read_b128)
    s16x8 bfr[4][2];
    #pragma unroll
    for (int ni = 0; ni < 4; ++ni)
      #pragma unroll
      for (int kk = 0; kk < 2; ++kk)
        bfr[ni][kk] = *reinterpret_cast<const s16x8*>(
            &Bs[b][(wc * 64 + ni * 16 + l15) * 64 + ((kk * 32 + l4 * 8) ^ rsw)]);
    // 4 phases: one 32-row A-quadrant each, 16 MFMA between barrier pair
    #pragma unroll
    for (int q = 0; q < 4; ++q) {
      s16x8 af[2][2];
      #pragma unroll
      for (int mi2 = 0; mi2 < 2; ++mi2)
        #pragma unroll
        for (int kk = 0; kk < 2; ++kk)
          af[mi2][kk] = *reinterpret_cast<const s16x8*>(
              &As[b][(wr * 128 + (q * 2 + mi2) * 16 + l15) * 64 +
                     ((kk * 32 + l4 * 8) ^ rsw)]);
      BAR();
      __builtin_amdgcn_s_setprio(1);
      #pragma unroll
      for (int mi2 = 0; mi2 < 2; ++mi2)
        #pragma unroll
        for (int ni = 0; ni < 4; ++ni)
          #pragma unroll
          for (int kk = 0; kk < 2; ++kk)
            acc[q * 2 + mi2][ni] = mfma16(af[mi2][kk], bfr[ni][kk], acc[q * 2 + mi2][ni]);
      __builtin_amdgcn_s_setprio(0);
      if (q < 3) BAR();
    }
    WAITVM0();   // next tile landed (covered by ~4 phases of compute)
    BAR();
  }

  #pragma unroll
  for (int mi = 0; mi < 8; ++mi) {
    #pragma unroll
    for (int ni = 0; ni < 4; ++ni) {
      int col = n0 + wc * 64 + ni * 16 + l15;
      #pragma unroll
      for (int j = 0; j < 4; ++j) {
        int row = m0 + wr * 128 + mi * 16 + l4 * 4 + j;
        float v = acc[mi][ni][j];
        size_t cidx = Coff + (size_t)row * ldc + col;
        if (EPI == 0) {
          Cb[cidx] = f2bf(fmaxf(v, 0.f));
        } else if (EPI == 1) {
          Cb[cidx] = f2bf(v);
        } else {
          float r = (col < Ksplit) ? R0[(size_t)row * 512 + col]
                                   : bf2f(R1[(size_t)row * 512 + (col - 512)]);
          float g = 1.0f / (1.0f + __expf(-v));
          Cf[cidx] = r * g;
        }
      }
    }
  }
}

// ======== P @ memory, 128x128 tile, counted-vmcnt dbuf, T2 swizzle, XCD remap ========
__global__ __launch_bounds__(256, 2) void gemm_pm_k(const u16* __restrict__ P,
                                                    const u16* __restrict__ MT,
                                                    u16* __restrict__ C) {
  __shared__ u16 As[2][128 * 64];
  __shared__ u16 Bs[2][128 * 64];
  const int l = blockIdx.x;
  const int logical = (l & 7) * 64 + (l >> 3);   // XCD-chunked over 512 blocks
  const int n0 = (logical & 3) * 128;
  const int m0 = ((logical >> 2) & 15) * 128;
  const int z = logical >> 6;
  const u16* Ab = P + (size_t)z * 2048 * 4096;
  const u16* Bb = MT + (size_t)z * 512 * 2048;
  u16* Cb = C + (size_t)z * 2048 * 512;
  const int tid = threadIdx.x, wave = tid >> 6, lane = tid & 63;
  const int wr = wave >> 1, wc = wave & 1;
  const int l15 = lane & 15, l4 = lane >> 4;
  const int srow = lane >> 3;
  const int scolsw = (((lane & 7) ^ (lane >> 3)) << 3);
  const int rsw = (l15 & 7) << 3;

  f32x4 acc[4][4];
  #pragma unroll
  for (int i = 0; i < 4; ++i)
    #pragma unroll
    for (int j = 0; j < 4; ++j) acc[i][j] = (f32x4){0.f, 0.f, 0.f, 0.f};

  auto stage = [&](int buf, int k0) {
    #pragma unroll
    for (int c = 0; c < 4; ++c) {
      int chunk = wave * 4 + c;                 // 0..15
      int row = chunk * 8 + srow;
      gload16(Ab + (size_t)(m0 + row) * 4096 + k0 + scolsw, &As[buf][chunk * 512]);
      gload16(Bb + (size_t)(n0 + row) * 2048 + k0 + scolsw, &Bs[buf][chunk * 512]);
    }
  };
  auto compute = [&](int cur) {
    __builtin_amdgcn_s_setprio(1);
    #pragma unroll
    for (int kk = 0; kk < 64; kk += 32) {
      s16x8 af[4], bfr[4];
      #pragma unroll
      for (int mi = 0; mi < 4; ++mi)
        af[mi] = *reinterpret_cast<const s16x8*>(
            &As[cur][(wr * 64 + mi * 16 + l15) * 64 + (((kk + l4 * 8) ^ rsw))]);
      #pragma unroll
      for (int ni = 0; ni < 4; ++ni)
        bfr[ni] = *reinterpret_cast<const s16x8*>(
            &Bs[cur][(wc * 64 + ni * 16 + l15) * 64 + (((kk + l4 * 8) ^ rsw))]);
      #pragma unroll
      for (int mi = 0; mi < 4; ++mi)
        #pragma unroll
        for (int ni = 0; ni < 4; ++ni)
          acc[mi][ni] = mfma16(af[mi], bfr[ni], acc[mi][ni]);
    }
    __builtin_amdgcn_s_setprio(0);
  };

  const int nt = 32;
  stage(0, 0);
  stage(1, 64);
  asm volatile("s_waitcnt vmcnt(8)" ::: "memory");
  BAR();
  for (int t = 0; t < nt; ++t) {
    const int cur = t & 1;
    compute(cur);
    BAR();
    if (t + 2 < nt) stage(cur, (t + 2) * 64);
    if (t + 1 < nt) {
      if (t + 2 < nt) { asm volatile("s_waitcnt vmcnt(8)" ::: "memory"); }
      else            { WAITVM0(); }
      BAR();
    }
  }

  #pragma unroll
  for (int mi = 0; mi < 4; ++mi) {
    #pragma unroll
    for (int ni = 0; ni < 4; ++ni) {
      int col = n0 + wc * 64 + ni * 16 + l15;
      #pragma unroll
      for (int j = 0; j < 4; ++j) {
        int row = m0 + wr * 64 + mi * 16 + l4 * 4 + j;
        Cb[(size_t)row * 512 + col] = f2bf(acc[mi][ni][j]);
      }
    }
  }
}

extern "C" void kernel_launch(void* const* d_in, const int* in_sizes, int n_in,
                              void* d_out, int out_size, void* d_ws, size_t ws_size,
                              hipStream_t stream) {
  const float* inputs = (const float*)d_in[0];  // [8,2048,512]
  const float* memory = (const float*)d_in[1];  // [8,2048,512]
  const int*   mask   = (const int*)d_in[2];    // [8,2048]
  const float* Wq     = (const float*)d_in[3];  // [512,512]
  const float* Wk     = (const float*)d_in[4];  // [512,512]
  const float* Wg     = (const float*)d_in[5];  // [1024,1024]
  float* out = (float*)d_out;                   // [8,2048,1024]

  char* ws = (char*)d_ws;
  size_t off = 0;
  auto alloc = [&](size_t bytes) {
    void* p = ws + off;
    off += (bytes + 255) & ~(size_t)255;
    return p;
  };
  u16* in_b  = (u16*)alloc(16384ULL * 512 * 2);   // inputs bf16
  u16* mem_b = (u16*)alloc(16384ULL * 512 * 2);   // memory bf16
  u16* memT  = (u16*)alloc(16384ULL * 512 * 2);   // memory^T bf16 [B][512][2048]
  u16* WqT   = (u16*)alloc(512ULL * 512 * 2);
  u16* WkT   = (u16*)alloc(512ULL * 512 * 2);
  u16* WgT   = (u16*)alloc(1024ULL * 1024 * 2);
  u16* q_b   = (u16*)alloc(16384ULL * 512 * 2);   // } contiguous pair
  u16* k_b   = (u16*)alloc(16384ULL * 512 * 2);   // }
  u16* sc    = (u16*)alloc(8ULL * 2048 * 4096 * 2);  // scores/P bf16, row stride 4096
  u16* att_b = (u16*)alloc(16384ULL * 512 * 2);
  (void)ws_size; (void)in_sizes; (void)n_in; (void)out_size;

  const int n8 = (16384 * 512) / 8;
  cvt_k<<<(n8 + 255) / 256, 256, 0, stream>>>(inputs, in_b, n8);
  cvt_k<<<(n8 + 255) / 256, 256, 0, stream>>>(memory, mem_b, n8);
  dim3 tb(32, 8);
  tcvt_k<<<dim3(16, 16, 1), tb, 0, stream>>>(Wq, WqT, 512, 512, 0, 0);
  tcvt_k<<<dim3(16, 16, 1), tb, 0, stream>>>(Wk, WkT, 512, 512, 0, 0);
  tcvt_k<<<dim3(32, 32, 1), tb, 0, stream>>>(Wg, WgT, 1024, 1024, 0, 0);
  tcvt_k<<<dim3(16, 64, 8), tb, 0, stream>>>(memory, memT, 2048, 512,
                                             2048LL * 512, 2048LL * 512);

  // [q|k] = relu([inputs|memory] @ [Wq or Wk]) — one M=32768 launch, 256 blocks
  gemm8p_k<0><<<256, 512, 0, stream>>>(
      in_b, nullptr, WqT, WkT, nullptr, q_b, nullptr, nullptr,
      512, 512, 512, 512, 512, 1 << 30, 16384, 2, 128, 256, 0, 0, 0);

  // scores[b] = q[b] @ k[b]^T -> bf16 directly in P layout (stride 4096)
  gemm8p_k<1><<<512, 512, 0, stream>>>(
      q_b, nullptr, k_b, k_b, nullptr, sc, nullptr, nullptr,
      2048, 512, 512, 512, 4096, 1 << 30, 1 << 30, 8, 8, 512,
      2048LL * 512, 2048LL * 512, 2048LL * 4096);

  // masked scaled softmax, bf16 in place
  softmax_k<<<16384, 256, 0, stream>>>(sc, mask, 0.044194173824159216f);

  // att[b] = P[b] @ memory[b] -> bf16, 512 blocks
  gemm_pm_k<<<512, 256, 0, stream>>>(sc, memT, att_b);

  // out = res * sigmoid(res @ Wg), res = [inputs | att], 256 blocks
  gemm8p_k<3><<<256, 512, 0, stream>>>(
      in_b, att_b, WgT, WgT, out, nullptr, inputs, att_b,
      1024, 1024, 512, 1024, 1024, 512, 1 << 30, 4, 64, 256, 0, 0, 0);
}

// Round 6
// 268.389 us; speedup vs baseline: 1.3123x; 1.0462x over previous
//
#include <hip/hip_runtime.h>

typedef unsigned short u16;
typedef unsigned int   u32;

typedef short s16x8 __attribute__((ext_vector_type(8)));
typedef float f32x4 __attribute__((ext_vector_type(4)));

static __device__ __forceinline__ u16 f2bf(float f) {
  u32 u = __float_as_uint(f);
  u = (u + 0x7fffu + ((u >> 16) & 1u)) >> 16;
  return (u16)u;
}
static __device__ __forceinline__ float bf2f(u16 h) {
  return __uint_as_float(((u32)h) << 16);
}
static __device__ __forceinline__ f32x4 mfma16(s16x8 a, s16x8 b, f32x4 c) {
  return __builtin_amdgcn_mfma_f32_16x16x32_bf16(a, b, c, 0, 0, 0);
}
static __device__ __forceinline__ void gload16(const u16* g, u16* l) {
  __builtin_amdgcn_global_load_lds(
      (const __attribute__((address_space(1))) void*)g,
      (__attribute__((address_space(3))) void*)l, 16, 0, 0);
}

// ---------------- flat f32 -> bf16 convert, 8 elems/thread ----------------
__global__ __launch_bounds__(256) void cvt_k(const float* __restrict__ in,
                                             u16* __restrict__ out, int n8) {
  int i = blockIdx.x * 256 + threadIdx.x;
  if (i >= n8) return;
  const float4* p = reinterpret_cast<const float4*>(in);
  float4 a = p[2 * i], b = p[2 * i + 1];
  union { u16 u[8]; uint4 v; } r;
  r.u[0] = f2bf(a.x); r.u[1] = f2bf(a.y); r.u[2] = f2bf(a.z); r.u[3] = f2bf(a.w);
  r.u[4] = f2bf(b.x); r.u[5] = f2bf(b.y); r.u[6] = f2bf(b.z); r.u[7] = f2bf(b.w);
  reinterpret_cast<uint4*>(out)[i] = r.v;
}

// ------------- transpose+convert: in [R,C] f32 -> out [C,R] bf16, batched -------------
__global__ void tcvt_k(const float* __restrict__ in, u16* __restrict__ out,
                       int R, int C, long long ibs, long long obs) {
  __shared__ float t[32][33];
  const float* ip = in + (size_t)blockIdx.z * ibs;
  u16* op = out + (size_t)blockIdx.z * obs;
  int r0 = blockIdx.y * 32, c0 = blockIdx.x * 32;
  int x = threadIdx.x, y = threadIdx.y;
  for (int i = y; i < 32; i += 8) t[i][x] = ip[(size_t)(r0 + i) * C + c0 + x];
  __syncthreads();
  for (int i = y; i < 32; i += 8) op[(size_t)(c0 + i) * R + r0 + x] = f2bf(t[x][i]);
}

// ------------- row softmax with mask, bf16 in-place (dense stride 2048) -------------
__global__ __launch_bounds__(256) void softmax_k(u16* __restrict__ P,
                                                 const int* __restrict__ mask,
                                                 float scale) {
  __shared__ float redm[4], reds[4];
  const int row = blockIdx.x;
  const int bb = row >> 11;
  const int tid = threadIdx.x;
  u16* p = P + (size_t)row * 2048;
  const int* mk = mask + (size_t)bb * 2048;
  uint4 raw = reinterpret_cast<const uint4*>(p)[tid];
  int4 ma = reinterpret_cast<const int4*>(mk)[2 * tid];
  int4 mc = reinterpret_cast<const int4*>(mk)[2 * tid + 1];
  float v[8];
  v[0] = ma.x ? bf2f((u16)(raw.x & 0xffff)) * scale : -1e30f;
  v[1] = ma.y ? bf2f((u16)(raw.x >> 16))    * scale : -1e30f;
  v[2] = ma.z ? bf2f((u16)(raw.y & 0xffff)) * scale : -1e30f;
  v[3] = ma.w ? bf2f((u16)(raw.y >> 16))    * scale : -1e30f;
  v[4] = mc.x ? bf2f((u16)(raw.z & 0xffff)) * scale : -1e30f;
  v[5] = mc.y ? bf2f((u16)(raw.z >> 16))    * scale : -1e30f;
  v[6] = mc.z ? bf2f((u16)(raw.w & 0xffff)) * scale : -1e30f;
  v[7] = mc.w ? bf2f((u16)(raw.w >> 16))    * scale : -1e30f;
  float mx = v[0];
  #pragma unroll
  for (int i = 1; i < 8; ++i) mx = fmaxf(mx, v[i]);
  for (int off = 32; off; off >>= 1) mx = fmaxf(mx, __shfl_xor(mx, off));
  if ((tid & 63) == 0) redm[tid >> 6] = mx;
  __syncthreads();
  mx = fmaxf(fmaxf(redm[0], redm[1]), fmaxf(redm[2], redm[3]));
  float sum = 0.f;
  #pragma unroll
  for (int i = 0; i < 8; ++i) { v[i] = __expf(v[i] - mx); sum += v[i]; }
  for (int off = 32; off; off >>= 1) sum += __shfl_xor(sum, off);
  if ((tid & 63) == 0) reds[tid >> 6] = sum;
  __syncthreads();
  sum = reds[0] + reds[1] + reds[2] + reds[3];
  float inv = 1.0f / sum;
  union { u16 u[8]; uint4 q; } r;
  #pragma unroll
  for (int i = 0; i < 8; ++i) r.u[i] = f2bf(v[i] * inv);
  reinterpret_cast<uint4*>(p)[tid] = r.q;
}

// ======== fully-templated 128x128 / BK=64 / single-buffer m97-structure GEMM ========
// A:[*,K](LDA) bf16, K-split A/A2 at KSPLIT. Bt:[N,K](LDB), M-split Bt/Bt2 at MSPLIT.
// Grid NWG 1-D, XCD-chunked. EPI 0: relu->bf16 Cb | 1: bf16 Cb | 3: gate -> f32 Cf.
template <int EPI, int NT, int NX, int NY,
          int LDA, int LDB, int LDC, int KSPLIT, int MSPLIT,
          long long ABS, long long BBS, long long CBS, int NWG>
__global__ __launch_bounds__(256) void g128(
    const u16* __restrict__ A, const u16* __restrict__ A2,
    const u16* __restrict__ Bt, const u16* __restrict__ Bt2,
    float* __restrict__ Cf, u16* __restrict__ Cb,
    const float* __restrict__ R0, const u16* __restrict__ R1) {
  __shared__ u16 As[128 * 64];
  __shared__ u16 Bs[128 * 64];
  const int bid = blockIdx.x;
  const int wgid = (bid & 7) * (NWG / 8) + (bid >> 3);   // XCD-chunked (NWG%8==0)
  const int bx = wgid % NX;
  const int by = (wgid / NX) % NY;
  const int bz = wgid / (NX * NY);
  const int tid = threadIdx.x;
  const int wave = tid >> 6, lane = tid & 63;
  const int m0 = by * 128, n0 = bx * 128;
  const int wr = wave >> 1, wc = wave & 1;            // 2x2 waves, each 64x64
  const int l15 = lane & 15, l4 = lane >> 4;
  const int srow = lane >> 3;                          // 0..7 in an 8-row chunk
  const int scolsw = (((lane & 7) ^ (lane >> 3)) << 3);  // T2 pre-swizzled src col
  const int rsw = (l15 & 7) << 3;                      // read-side XOR (u16 elems)
  const u16* Bbase = ((m0 < MSPLIT) ? Bt : Bt2) + (size_t)bz * BBS;

  f32x4 acc[4][4];
  #pragma unroll
  for (int i = 0; i < 4; ++i)
    #pragma unroll
    for (int j = 0; j < 4; ++j) acc[i][j] = (f32x4){0.f, 0.f, 0.f, 0.f};

  for (int t = 0; t < NT; ++t) {
    const int k0 = t * 64;
    const u16* Ab;
    int kl;
    if (k0 < KSPLIT) { Ab = A + (size_t)bz * ABS;  kl = k0; }
    else             { Ab = A2 + (size_t)bz * ABS; kl = k0 - KSPLIT; }
    __syncthreads();                    // WAR: prev tile's reads complete
    #pragma unroll
    for (int c = 0; c < 4; ++c) {
      int chunk = wave * 4 + c;         // 0..15, 1KB each (8 rows x 128B)
      int row = chunk * 8 + srow;
      gload16(Ab + (size_t)(m0 + row) * LDA + kl + scolsw, &As[chunk * 512]);
      gload16(Bbase + (size_t)(n0 + row) * LDB + k0 + scolsw, &Bs[chunk * 512]);
    }
    __syncthreads();                    // vmcnt(0) drain: tile resident
    #pragma unroll
    for (int kk = 0; kk < 64; kk += 32) {
      s16x8 af[4], bfr[4];
      #pragma unroll
      for (int mi = 0; mi < 4; ++mi)
        af[mi] = *reinterpret_cast<const s16x8*>(
            &As[(wr * 64 + mi * 16 + l15) * 64 + ((kk + l4 * 8) ^ rsw)]);
      #pragma unroll
      for (int ni = 0; ni < 4; ++ni)
        bfr[ni] = *reinterpret_cast<const s16x8*>(
            &Bs[(wc * 64 + ni * 16 + l15) * 64 + ((kk + l4 * 8) ^ rsw)]);
      #pragma unroll
      for (int mi = 0; mi < 4; ++mi)
        #pragma unroll
        for (int ni = 0; ni < 4; ++ni)
          acc[mi][ni] = mfma16(af[mi], bfr[ni], acc[mi][ni]);
    }
  }

  #pragma unroll
  for (int mi = 0; mi < 4; ++mi) {
    #pragma unroll
    for (int ni = 0; ni < 4; ++ni) {
      int col = n0 + wc * 64 + ni * 16 + l15;
      #pragma unroll
      for (int j = 0; j < 4; ++j) {
        int row = m0 + wr * 64 + mi * 16 + l4 * 4 + j;
        float v = acc[mi][ni][j];
        size_t cidx = (size_t)bz * CBS + (size_t)row * LDC + col;
        if (EPI == 0) {
          Cb[cidx] = f2bf(fmaxf(v, 0.f));
        } else if (EPI == 1) {
          Cb[cidx] = f2bf(v);
        } else {
          float r = (col < 512) ? R0[(size_t)row * 512 + col]
                                : bf2f(R1[(size_t)row * 512 + (col - 512)]);
          float g = 1.0f / (1.0f + __expf(-v));
          Cf[cidx] = r * g;
        }
      }
    }
  }
}

// ======== P @ memory (control kernel, frozen from R4/R5; P stride now 2048) ========
__global__ __launch_bounds__(256, 2) void gemm_pm_k(const u16* __restrict__ P,
                                                    const u16* __restrict__ MT,
                                                    u16* __restrict__ C) {
  __shared__ u16 As[2][128 * 64];
  __shared__ u16 Bs[2][128 * 64];
  const int l = blockIdx.x;
  const int logical = (l & 7) * 64 + (l >> 3);   // XCD-chunked over 512 blocks
  const int n0 = (logical & 3) * 128;
  const int m0 = ((logical >> 2) & 15) * 128;
  const int z = logical >> 6;
  const u16* Ab = P + (size_t)z * 2048 * 2048;
  const u16* Bb = MT + (size_t)z * 512 * 2048;
  u16* Cb = C + (size_t)z * 2048 * 512;
  const int tid = threadIdx.x, wave = tid >> 6, lane = tid & 63;
  const int wr = wave >> 1, wc = wave & 1;
  const int l15 = lane & 15, l4 = lane >> 4;
  const int srow = lane >> 3;
  const int scolsw = (((lane & 7) ^ (lane >> 3)) << 3);
  const int rsw = (l15 & 7) << 3;

  f32x4 acc[4][4];
  #pragma unroll
  for (int i = 0; i < 4; ++i)
    #pragma unroll
    for (int j = 0; j < 4; ++j) acc[i][j] = (f32x4){0.f, 0.f, 0.f, 0.f};

  auto stage = [&](int buf, int k0) {
    #pragma unroll
    for (int c = 0; c < 4; ++c) {
      int chunk = wave * 4 + c;                 // 0..15
      int row = chunk * 8 + srow;
      gload16(Ab + (size_t)(m0 + row) * 2048 + k0 + scolsw, &As[buf][chunk * 512]);
      gload16(Bb + (size_t)(n0 + row) * 2048 + k0 + scolsw, &Bs[buf][chunk * 512]);
    }
  };
  auto compute = [&](int cur) {
    __builtin_amdgcn_s_setprio(1);
    #pragma unroll
    for (int kk = 0; kk < 64; kk += 32) {
      s16x8 af[4], bfr[4];
      #pragma unroll
      for (int mi = 0; mi < 4; ++mi)
        af[mi] = *reinterpret_cast<const s16x8*>(
            &As[cur][(wr * 64 + mi * 16 + l15) * 64 + (((kk + l4 * 8) ^ rsw))]);
      #pragma unroll
      for (int ni = 0; ni < 4; ++ni)
        bfr[ni] = *reinterpret_cast<const s16x8*>(
            &Bs[cur][(wc * 64 + ni * 16 + l15) * 64 + (((kk + l4 * 8) ^ rsw))]);
      #pragma unroll
      for (int mi = 0; mi < 4; ++mi)
        #pragma unroll
        for (int ni = 0; ni < 4; ++ni)
          acc[mi][ni] = mfma16(af[mi], bfr[ni], acc[mi][ni]);
    }
    __builtin_amdgcn_s_setprio(0);
  };

  const int nt = 32;
  stage(0, 0);
  stage(1, 64);
  asm volatile("s_waitcnt vmcnt(8)" ::: "memory");
  __builtin_amdgcn_s_barrier();
  for (int t = 0; t < nt; ++t) {
    const int cur = t & 1;
    compute(cur);
    __builtin_amdgcn_s_barrier();
    if (t + 2 < nt) stage(cur, (t + 2) * 64);
    if (t + 1 < nt) {
      if (t + 2 < nt) { asm volatile("s_waitcnt vmcnt(8)" ::: "memory"); }
      else            { asm volatile("s_waitcnt vmcnt(0)" ::: "memory"); }
      __builtin_amdgcn_s_barrier();
    }
  }

  #pragma unroll
  for (int mi = 0; mi < 4; ++mi) {
    #pragma unroll
    for (int ni = 0; ni < 4; ++ni) {
      int col = n0 + wc * 64 + ni * 16 + l15;
      #pragma unroll
      for (int j = 0; j < 4; ++j) {
        int row = m0 + wr * 64 + mi * 16 + l4 * 4 + j;
        Cb[(size_t)row * 512 + col] = f2bf(acc[mi][ni][j]);
      }
    }
  }
}

extern "C" void kernel_launch(void* const* d_in, const int* in_sizes, int n_in,
                              void* d_out, int out_size, void* d_ws, size_t ws_size,
                              hipStream_t stream) {
  const float* inputs = (const float*)d_in[0];  // [8,2048,512]
  const float* memory = (const float*)d_in[1];  // [8,2048,512]
  const int*   mask   = (const int*)d_in[2];    // [8,2048]
  const float* Wq     = (const float*)d_in[3];  // [512,512]
  const float* Wk     = (const float*)d_in[4];  // [512,512]
  const float* Wg     = (const float*)d_in[5];  // [1024,1024]
  float* out = (float*)d_out;                   // [8,2048,1024]

  char* ws = (char*)d_ws;
  size_t off = 0;
  auto alloc = [&](size_t bytes) {
    void* p = ws + off;
    off += (bytes + 255) & ~(size_t)255;
    return p;
  };
  u16* in_b  = (u16*)alloc(16384ULL * 512 * 2);   // } contiguous pair: [inputs|memory]
  u16* mem_b = (u16*)alloc(16384ULL * 512 * 2);   // }
  u16* memT  = (u16*)alloc(16384ULL * 512 * 2);   // memory^T bf16 [B][512][2048]
  u16* WqT   = (u16*)alloc(512ULL * 512 * 2);
  u16* WkT   = (u16*)alloc(512ULL * 512 * 2);
  u16* WgT   = (u16*)alloc(1024ULL * 1024 * 2);
  u16* q_b   = (u16*)alloc(16384ULL * 512 * 2);   // } contiguous pair: [q|k]
  u16* k_b   = (u16*)alloc(16384ULL * 512 * 2);   // }
  u16* sc    = (u16*)alloc(8ULL * 2048 * 2048 * 2);  // scores/P bf16 dense
  u16* att_b = (u16*)alloc(16384ULL * 512 * 2);
  (void)ws_size; (void)in_sizes; (void)n_in; (void)out_size; (void)mem_b;

  const int n8 = (16384 * 512) / 8;
  cvt_k<<<(n8 + 255) / 256, 256, 0, stream>>>(inputs, in_b, n8);
  cvt_k<<<(n8 + 255) / 256, 256, 0, stream>>>(memory, in_b + 16384ULL * 512, n8);
  dim3 tb(32, 8);
  tcvt_k<<<dim3(16, 16, 1), tb, 0, stream>>>(Wq, WqT, 512, 512, 0, 0);
  tcvt_k<<<dim3(16, 16, 1), tb, 0, stream>>>(Wk, WkT, 512, 512, 0, 0);
  tcvt_k<<<dim3(32, 32, 1), tb, 0, stream>>>(Wg, WgT, 1024, 1024, 0, 0);
  tcvt_k<<<dim3(16, 64, 8), tb, 0, stream>>>(memory, memT, 2048, 512,
                                             2048LL * 512, 2048LL * 512);

  // [q|k] = relu([inputs|memory] @ [Wq or Wk])  — M=32768, N=512, K=512
  g128<0, 8, 4, 256, 512, 512, 512, (1 << 30), 16384, 0, 0, 0, 1024>
      <<<1024, 256, 0, stream>>>(in_b, nullptr, WqT, WkT,
                                 nullptr, q_b, nullptr, nullptr);

  // scores[b] = q[b] @ k[b]^T -> bf16 dense [2048][2048] per batch
  g128<1, 8, 16, 16, 512, 512, 2048, (1 << 30), (1 << 30),
       2048LL * 512, 2048LL * 512, 2048LL * 2048, 2048>
      <<<2048, 256, 0, stream>>>(q_b, nullptr, k_b, k_b,
                                 nullptr, sc, nullptr, nullptr);

  // masked scaled softmax, bf16 in place (dense)
  softmax_k<<<16384, 256, 0, stream>>>(sc, mask, 0.044194173824159216f);

  // att[b] = P[b] @ memory[b] -> bf16
  gemm_pm_k<<<512, 256, 0, stream>>>(sc, memT, att_b);

  // out = res * sigmoid(res @ Wg), res = [inputs | att]; A-split at K=512
  g128<3, 16, 8, 128, 512, 1024, 1024, 512, (1 << 30), 0, 0, 0, 1024>
      <<<1024, 256, 0, stream>>>(in_b, att_b, WgT, WgT,
                                 out, nullptr, inputs, att_b);
}

// Round 7
// 235.522 us; speedup vs baseline: 1.4954x; 1.1396x over previous
//
#include <hip/hip_runtime.h>

typedef unsigned short u16;
typedef unsigned int   u32;

typedef short s16x8 __attribute__((ext_vector_type(8)));
typedef float f32x4 __attribute__((ext_vector_type(4)));

static __device__ __forceinline__ u16 f2bf(float f) {
  u32 u = __float_as_uint(f);
  u = (u + 0x7fffu + ((u >> 16) & 1u)) >> 16;
  return (u16)u;
}
static __device__ __forceinline__ float bf2f(u16 h) {
  return __uint_as_float(((u32)h) << 16);
}
static __device__ __forceinline__ f32x4 mfma16(s16x8 a, s16x8 b, f32x4 c) {
  return __builtin_amdgcn_mfma_f32_16x16x32_bf16(a, b, c, 0, 0, 0);
}
static __device__ __forceinline__ void gload16(const u16* g, u16* l) {
  __builtin_amdgcn_global_load_lds(
      (const __attribute__((address_space(1))) void*)g,
      (__attribute__((address_space(3))) void*)l, 16, 0, 0);
}

#define WAITVM8() asm volatile("s_waitcnt vmcnt(8)" ::: "memory")
#define WAITVM0() asm volatile("s_waitcnt vmcnt(0)" ::: "memory")
#define BAR()                                  \
  do {                                         \
    asm volatile("" ::: "memory");             \
    __builtin_amdgcn_s_barrier();              \
    asm volatile("" ::: "memory");             \
  } while (0)

// ---------------- flat f32 -> bf16 convert, 8 elems/thread ----------------
__global__ __launch_bounds__(256) void cvt_k(const float* __restrict__ in,
                                             u16* __restrict__ out, int n8) {
  int i = blockIdx.x * 256 + threadIdx.x;
  if (i >= n8) return;
  const float4* p = reinterpret_cast<const float4*>(in);
  float4 a = p[2 * i], b = p[2 * i + 1];
  union { u16 u[8]; uint4 v; } r;
  r.u[0] = f2bf(a.x); r.u[1] = f2bf(a.y); r.u[2] = f2bf(a.z); r.u[3] = f2bf(a.w);
  r.u[4] = f2bf(b.x); r.u[5] = f2bf(b.y); r.u[6] = f2bf(b.z); r.u[7] = f2bf(b.w);
  reinterpret_cast<uint4*>(out)[i] = r.v;
}

// ------------- transpose+convert: in [R,C] f32 -> out [C,R] bf16, batched -------------
__global__ void tcvt_k(const float* __restrict__ in, u16* __restrict__ out,
                       int R, int C, long long ibs, long long obs) {
  __shared__ float t[32][33];
  const float* ip = in + (size_t)blockIdx.z * ibs;
  u16* op = out + (size_t)blockIdx.z * obs;
  int r0 = blockIdx.y * 32, c0 = blockIdx.x * 32;
  int x = threadIdx.x, y = threadIdx.y;
  for (int i = y; i < 32; i += 8) t[i][x] = ip[(size_t)(r0 + i) * C + c0 + x];
  __syncthreads();
  for (int i = y; i < 32; i += 8) op[(size_t)(c0 + i) * R + r0 + x] = f2bf(t[x][i]);
}

// ------------- row softmax with mask, bf16 in-place (dense stride 2048) -------------
__global__ __launch_bounds__(256) void softmax_k(u16* __restrict__ P,
                                                 const int* __restrict__ mask,
                                                 float scale) {
  __shared__ float redm[4], reds[4];
  const int row = blockIdx.x;
  const int bb = row >> 11;
  const int tid = threadIdx.x;
  u16* p = P + (size_t)row * 2048;
  const int* mk = mask + (size_t)bb * 2048;
  uint4 raw = reinterpret_cast<const uint4*>(p)[tid];
  int4 ma = reinterpret_cast<const int4*>(mk)[2 * tid];
  int4 mc = reinterpret_cast<const int4*>(mk)[2 * tid + 1];
  float v[8];
  v[0] = ma.x ? bf2f((u16)(raw.x & 0xffff)) * scale : -1e30f;
  v[1] = ma.y ? bf2f((u16)(raw.x >> 16))    * scale : -1e30f;
  v[2] = ma.z ? bf2f((u16)(raw.y & 0xffff)) * scale : -1e30f;
  v[3] = ma.w ? bf2f((u16)(raw.y >> 16))    * scale : -1e30f;
  v[4] = mc.x ? bf2f((u16)(raw.z & 0xffff)) * scale : -1e30f;
  v[5] = mc.y ? bf2f((u16)(raw.z >> 16))    * scale : -1e30f;
  v[6] = mc.z ? bf2f((u16)(raw.w & 0xffff)) * scale : -1e30f;
  v[7] = mc.w ? bf2f((u16)(raw.w >> 16))    * scale : -1e30f;
  float mx = v[0];
  #pragma unroll
  for (int i = 1; i < 8; ++i) mx = fmaxf(mx, v[i]);
  for (int off = 32; off; off >>= 1) mx = fmaxf(mx, __shfl_xor(mx, off));
  if ((tid & 63) == 0) redm[tid >> 6] = mx;
  __syncthreads();
  mx = fmaxf(fmaxf(redm[0], redm[1]), fmaxf(redm[2], redm[3]));
  float sum = 0.f;
  #pragma unroll
  for (int i = 0; i < 8; ++i) { v[i] = __expf(v[i] - mx); sum += v[i]; }
  for (int off = 32; off; off >>= 1) sum += __shfl_xor(sum, off);
  if ((tid & 63) == 0) reds[tid >> 6] = sum;
  __syncthreads();
  sum = reds[0] + reds[1] + reds[2] + reds[3];
  float inv = 1.0f / sum;
  union { u16 u[8]; uint4 q; } r;
  #pragma unroll
  for (int i = 0; i < 8; ++i) r.u[i] = f2bf(v[i] * inv);
  reinterpret_cast<uint4*>(p)[tid] = r.q;
}

// ======== unified 128x128 / BK=64 dbuf counted-vmcnt GEMM, LDS-coalesced epilogue ========
// A:[*,K](LDA) bf16, K-split A/A2 at KSPLIT (same LDA). Bt:[N,K](LDB), M-split at MSPLIT.
// 1-D grid NWG (multiple of 8), XCD-chunked. EPI 0: relu->bf16 Cb | 1: bf16 Cb |
// 3: gate -> f32 Cf (R0 f32 cols<512, R1 bf16 cols>=512).
template <int EPI, int NT, int NX, int NY,
          int LDA, int LDB, int LDC, int KSPLIT, int MSPLIT,
          long long ABS, long long BBS, long long CBS, int NWG>
__global__ __launch_bounds__(256, 2) void gdb(
    const u16* __restrict__ A, const u16* __restrict__ A2,
    const u16* __restrict__ Bt, const u16* __restrict__ Bt2,
    float* __restrict__ Cf, u16* __restrict__ Cb,
    const float* __restrict__ R0, const u16* __restrict__ R1) {
  __shared__ u16 As[2][128 * 64];
  __shared__ u16 Bs[2][128 * 64];
  const int bid = blockIdx.x;
  const int wgid = (bid & 7) * (NWG / 8) + (bid >> 3);   // XCD-chunked
  const int bx = wgid % NX;
  const int by = (wgid / NX) % NY;
  const int bz = wgid / (NX * NY);
  const int tid = threadIdx.x;
  const int wave = tid >> 6, lane = tid & 63;
  const int m0 = by * 128, n0 = bx * 128;
  const int wr = wave >> 1, wc = wave & 1;               // 2x2 waves, 64x64 each
  const int l15 = lane & 15, l4 = lane >> 4;
  const int srow = lane >> 3;
  const int scolsw = (((lane & 7) ^ (lane >> 3)) << 3);  // T2 pre-swizzled src col
  const int rsw = (l15 & 7) << 3;                        // read-side XOR
  const u16* Bbase = ((m0 < MSPLIT) ? Bt : Bt2) + (size_t)bz * BBS;
  const u16* Abase0 = A + (size_t)bz * ABS;
  const u16* Abase1 = A2 + (size_t)bz * ABS;

  f32x4 acc[4][4];
  #pragma unroll
  for (int i = 0; i < 4; ++i)
    #pragma unroll
    for (int j = 0; j < 4; ++j) acc[i][j] = (f32x4){0.f, 0.f, 0.f, 0.f};

  auto stage = [&](int buf, int k0) {
    const u16* Ab;
    int kl;
    if (k0 < KSPLIT) { Ab = Abase0; kl = k0; }
    else             { Ab = Abase1; kl = k0 - KSPLIT; }
    #pragma unroll
    for (int c = 0; c < 4; ++c) {
      int chunk = wave * 4 + c;                          // 0..15, 1KB each
      int row = chunk * 8 + srow;
      gload16(Ab + (size_t)(m0 + row) * LDA + kl + scolsw, &As[buf][chunk * 512]);
      gload16(Bbase + (size_t)(n0 + row) * LDB + k0 + scolsw, &Bs[buf][chunk * 512]);
    }
  };
  auto compute = [&](int cur) {
    __builtin_amdgcn_s_setprio(1);
    #pragma unroll
    for (int kk = 0; kk < 64; kk += 32) {
      s16x8 af[4], bfr[4];
      #pragma unroll
      for (int mi = 0; mi < 4; ++mi)
        af[mi] = *reinterpret_cast<const s16x8*>(
            &As[cur][(wr * 64 + mi * 16 + l15) * 64 + ((kk + l4 * 8) ^ rsw)]);
      #pragma unroll
      for (int ni = 0; ni < 4; ++ni)
        bfr[ni] = *reinterpret_cast<const s16x8*>(
            &Bs[cur][(wc * 64 + ni * 16 + l15) * 64 + ((kk + l4 * 8) ^ rsw)]);
      #pragma unroll
      for (int mi = 0; mi < 4; ++mi)
        #pragma unroll
        for (int ni = 0; ni < 4; ++ni)
          acc[mi][ni] = mfma16(af[mi], bfr[ni], acc[mi][ni]);
    }
    __builtin_amdgcn_s_setprio(0);
  };

  stage(0, 0);
  stage(1, 64);
  WAITVM8();
  BAR();
  for (int t = 0; t < NT; ++t) {
    const int cur = t & 1;
    compute(cur);
    BAR();                                   // WAR: buf[cur] free
    if (t + 2 < NT) stage(cur, (t + 2) * 64);
    if (t + 1 < NT) {
      if (t + 2 < NT) { WAITVM8(); } else { WAITVM0(); }
      BAR();                                 // RAW: tile t+1 resident for all
    }
  }

  // ---- epilogue: stage C chunks through LDS, store coalesced ----
  float* LF = (float*)(&As[0][0]);           // 32x132 f32 = 16.9KB (overlays As)
  const int er = tid >> 3;                   // 0..31 local row
  const int ec = (tid & 7) * 16;             // col base, 16 f32 per thread
  #pragma unroll
  for (int mi = 0; mi < 4; ++mi) {
    __syncthreads();                          // prev chunk consumed / K-loop done
    #pragma unroll
    for (int ni = 0; ni < 4; ++ni) {
      int lcol = wc * 64 + ni * 16 + l15;
      #pragma unroll
      for (int j = 0; j < 4; ++j)
        LF[(wr * 16 + l4 * 4 + j) * 132 + lcol] = acc[mi][ni][j];
    }
    __syncthreads();
    int grow = m0 + mi * 16 + (er & 15) + (er >> 4) * 64;
    int gcol = n0 + ec;
    float v[16];
    #pragma unroll
    for (int i = 0; i < 4; ++i)
      *reinterpret_cast<f32x4*>(&v[4 * i]) =
          *reinterpret_cast<const f32x4*>(&LF[er * 132 + ec + 4 * i]);
    if (EPI == 3) {
      float* o = Cf + (size_t)bz * CBS + (size_t)grow * LDC + gcol;
      if (n0 < 512) {
        const float* r0 = R0 + (size_t)grow * 512 + gcol;
        #pragma unroll
        for (int i = 0; i < 16; ++i) {
          float g = 1.0f / (1.0f + __expf(-v[i]));
          v[i] = r0[i] * g;
        }
      } else {
        const u16* r1 = R1 + (size_t)grow * 512 + (gcol - 512);
        #pragma unroll
        for (int i = 0; i < 16; ++i) {
          float g = 1.0f / (1.0f + __expf(-v[i]));
          v[i] = bf2f(r1[i]) * g;
        }
      }
      #pragma unroll
      for (int i = 0; i < 4; ++i)
        *reinterpret_cast<float4*>(&o[4 * i]) = *reinterpret_cast<float4*>(&v[4 * i]);
    } else {
      union { u16 u[16]; uint4 q[2]; } pk;
      #pragma unroll
      for (int i = 0; i < 16; ++i)
        pk.u[i] = f2bf(EPI == 0 ? fmaxf(v[i], 0.f) : v[i]);
      u16* o = Cb + (size_t)bz * CBS + (size_t)grow * LDC + gcol;
      reinterpret_cast<uint4*>(o)[0] = pk.q[0];
      reinterpret_cast<uint4*>(o)[1] = pk.q[1];
    }
  }
}

extern "C" void kernel_launch(void* const* d_in, const int* in_sizes, int n_in,
                              void* d_out, int out_size, void* d_ws, size_t ws_size,
                              hipStream_t stream) {
  const float* inputs = (const float*)d_in[0];  // [8,2048,512]
  const float* memory = (const float*)d_in[1];  // [8,2048,512]
  const int*   mask   = (const int*)d_in[2];    // [8,2048]
  const float* Wq     = (const float*)d_in[3];  // [512,512]
  const float* Wk     = (const float*)d_in[4];  // [512,512]
  const float* Wg     = (const float*)d_in[5];  // [1024,1024]
  float* out = (float*)d_out;                   // [8,2048,1024]

  char* ws = (char*)d_ws;
  size_t off = 0;
  auto alloc = [&](size_t bytes) {
    void* p = ws + off;
    off += (bytes + 255) & ~(size_t)255;
    return p;
  };
  u16* in_b  = (u16*)alloc(16384ULL * 512 * 2);   // } contiguous pair [inputs|memory]
  u16* mem_b = (u16*)alloc(16384ULL * 512 * 2);   // }
  u16* memT  = (u16*)alloc(16384ULL * 512 * 2);   // memory^T bf16 [B][512][2048]
  u16* WqT   = (u16*)alloc(512ULL * 512 * 2);
  u16* WkT   = (u16*)alloc(512ULL * 512 * 2);
  u16* WgT   = (u16*)alloc(1024ULL * 1024 * 2);
  u16* q_b   = (u16*)alloc(16384ULL * 512 * 2);   // } contiguous pair [q|k]
  u16* k_b   = (u16*)alloc(16384ULL * 512 * 2);   // }
  u16* sc    = (u16*)alloc(8ULL * 2048 * 2048 * 2);  // scores/P bf16 dense
  u16* att_b = (u16*)alloc(16384ULL * 512 * 2);
  (void)ws_size; (void)in_sizes; (void)n_in; (void)out_size; (void)mem_b;

  const int n8 = (16384 * 512) / 8;
  cvt_k<<<(n8 + 255) / 256, 256, 0, stream>>>(inputs, in_b, n8);
  cvt_k<<<(n8 + 255) / 256, 256, 0, stream>>>(memory, in_b + 16384ULL * 512, n8);
  dim3 tb(32, 8);
  tcvt_k<<<dim3(16, 16, 1), tb, 0, stream>>>(Wq, WqT, 512, 512, 0, 0);
  tcvt_k<<<dim3(16, 16, 1), tb, 0, stream>>>(Wk, WkT, 512, 512, 0, 0);
  tcvt_k<<<dim3(32, 32, 1), tb, 0, stream>>>(Wg, WgT, 1024, 1024, 0, 0);
  tcvt_k<<<dim3(16, 64, 8), tb, 0, stream>>>(memory, memT, 2048, 512,
                                             2048LL * 512, 2048LL * 512);

  const int BIG = 1 << 30;

  // [q|k] = relu([inputs|memory] @ [Wq or Wk])  M=32768 N=512 K=512
  gdb<0, 8, 4, 256, 512, 512, 512, (1 << 30), 16384, 0, 0, 0, 1024>
      <<<1024, 256, 0, stream>>>(in_b, in_b, WqT, WkT, nullptr, q_b,
                                 nullptr, nullptr);

  // scores[b] = q[b] @ k[b]^T -> bf16 dense [2048][2048], one batch per XCD
  gdb<1, 8, 16, 16, 512, 512, 2048, (1 << 30), (1 << 30),
      2048LL * 512, 2048LL * 512, 2048LL * 2048, 2048>
      <<<2048, 256, 0, stream>>>(q_b, q_b, k_b, k_b, nullptr, sc,
                                 nullptr, nullptr);

  // masked scaled softmax, bf16 in place (dense)
  softmax_k<<<16384, 256, 0, stream>>>(sc, mask, 0.044194173824159216f);

  // att[b] = P[b] @ memory[b] -> bf16  (M=2048 N=512 K=2048 per batch)
  gdb<1, 32, 4, 16, 2048, 2048, 512, (1 << 30), (1 << 30),
      2048LL * 2048, 512LL * 2048, 2048LL * 512, 512>
      <<<512, 256, 0, stream>>>(sc, sc, memT, memT, nullptr, att_b,
                                nullptr, nullptr);

  // out = res * sigmoid(res @ Wg), res = [inputs | att]; A K-split at 512
  gdb<3, 16, 8, 128, 512, 1024, 1024, 512, (1 << 30), 0, 0, 0, 1024>
      <<<1024, 256, 0, stream>>>(in_b, att_b, WgT, WgT, out, nullptr,
                                 inputs, att_b);
  (void)BIG;
}